// Round 1
// baseline (890.853 us; speedup 1.0000x reference)
//
#include <hip/hip_runtime.h>
#include <math.h>

#define N_NODES 50000
#define N_EDGES 600000
#define D 128
#define NLAYERS 3
#define BN_EPS 1e-5f

// ---------------- CSR build ----------------
__global__ void k_hist(const int* __restrict__ dst, int* __restrict__ cnt) {
    int e = blockIdx.x * blockDim.x + threadIdx.x;
    if (e < N_EDGES) atomicAdd(&cnt[dst[e]], 1);
}

// single-block exclusive scan over N_NODES counts -> row_ptr[0..N_NODES]
__global__ void k_scan(const int* __restrict__ cnt, int* __restrict__ row_ptr) {
    __shared__ int sm[1024];
    __shared__ int carry_s;
    if (threadIdx.x == 0) carry_s = 0;
    __syncthreads();
    for (int base = 0; base < N_NODES; base += 1024) {
        int i = base + threadIdx.x;
        int v = (i < N_NODES) ? cnt[i] : 0;
        sm[threadIdx.x] = v;
        __syncthreads();
        for (int off = 1; off < 1024; off <<= 1) {
            int t = (threadIdx.x >= off) ? sm[threadIdx.x - off] : 0;
            __syncthreads();
            sm[threadIdx.x] += t;
            __syncthreads();
        }
        int incl = sm[threadIdx.x];
        int blocktot = sm[1023];
        if (i < N_NODES) row_ptr[i] = carry_s + incl - v;
        __syncthreads();
        if (threadIdx.x == 0) carry_s += blocktot;
        __syncthreads();
    }
    if (threadIdx.x == 0) row_ptr[N_NODES] = carry_s;
}

__global__ void k_copy_int(const int* __restrict__ a, int* __restrict__ b, int n) {
    int i = blockIdx.x * blockDim.x + threadIdx.x;
    if (i < n) b[i] = a[i];
}

__global__ void k_fill(const int* __restrict__ src, const int* __restrict__ dst,
                       int* __restrict__ row_fill, int* __restrict__ edge_sorted) {
    int e = blockIdx.x * blockDim.x + threadIdx.x;
    if (e < N_EDGES) {
        int pos = atomicAdd(&row_fill[dst[e]], 1);
        edge_sorted[pos] = src[e];
    }
}

// ---------------- mean aggregation (gather via CSR): one wave per node ----------------
__global__ void k_agg(const float* __restrict__ h, const int* __restrict__ edge_sorted,
                      const int* __restrict__ row_ptr, float* __restrict__ meanbuf) {
    int wave  = (blockIdx.x * blockDim.x + threadIdx.x) >> 6;
    int lane  = threadIdx.x & 63;
    int nwave = (gridDim.x * blockDim.x) >> 6;
    const float2* hp = (const float2*)h;
    for (int node = wave; node < N_NODES; node += nwave) {
        int beg = row_ptr[node], end = row_ptr[node + 1];
        float ax = 0.f, ay = 0.f;
        for (int j = beg; j < end; ++j) {
            int s = edge_sorted[j];
            float2 v = hp[(size_t)s * 64 + lane];
            ax += v.x; ay += v.y;
        }
        float inv = 1.0f / fmaxf((float)(end - beg), 1.0f);
        float2 o; o.x = ax * inv; o.y = ay * inv;
        ((float2*)meanbuf)[(size_t)node * 64 + lane] = o;
    }
}

// ---------------- fp32 GEMM: pre[n][j] = sum_k mean[n][k]*Wl[k][j] + h[n][k]*Wr[k][j] + bias[j]
// block: 256 thr, tile 64 rows x 128 cols, K=256 in chunks of 32
__global__ __launch_bounds__(256) void k_gemm(const float* __restrict__ Amean,
                                              const float* __restrict__ Ah,
                                              const float* __restrict__ Wl,
                                              const float* __restrict__ Wr,
                                              const float* __restrict__ bias,
                                              float* __restrict__ pre) {
    __shared__ float As[64][36];   // +4 pad
    __shared__ float Ws[32][128];
    int tid = threadIdx.x;
    int rg = tid >> 4;     // 0..15 -> rows rg*4..rg*4+3
    int cg = tid & 15;     // 0..15 -> cols cg*4..+3 and 64+cg*4..+3
    int row0 = blockIdx.x * 64;

    float acc[4][8];
#pragma unroll
    for (int i = 0; i < 4; ++i)
#pragma unroll
        for (int c = 0; c < 8; ++c) acc[i][c] = 0.f;

    for (int kt = 0; kt < 8; ++kt) {
        const float* Asrc = (kt < 4) ? Amean : Ah;
        const float* Wsrc = (kt < 4) ? Wl : Wr;
        int kbase = (kt & 3) * 32;
        // load A tile: 64 rows x 32 floats = 512 float4
#pragma unroll
        for (int t = 0; t < 2; ++t) {
            int idx = tid + t * 256;          // 0..511
            int r = idx >> 3;                 // 8 float4 per row
            int kq = (idx & 7) << 2;
            int grow = row0 + r;
            float4 v = make_float4(0.f, 0.f, 0.f, 0.f);
            if (grow < N_NODES) v = *(const float4*)(Asrc + (size_t)grow * D + kbase + kq);
            *(float4*)&As[r][kq] = v;
        }
        // load W tile: 32 rows x 128 floats = 1024 float4
#pragma unroll
        for (int t = 0; t < 4; ++t) {
            int idx = tid + t * 256;          // 0..1023
            int r = idx >> 5;                 // 32 float4 per row
            int c = (idx & 31) << 2;
            *(float4*)&Ws[r][c] = *(const float4*)(Wsrc + (size_t)(kbase + r) * D + c);
        }
        __syncthreads();
#pragma unroll
        for (int k = 0; k < 32; ++k) {
            float a0 = As[rg * 4 + 0][k];
            float a1 = As[rg * 4 + 1][k];
            float a2 = As[rg * 4 + 2][k];
            float a3 = As[rg * 4 + 3][k];
            float w[8];
            *(float4*)&w[0] = *(const float4*)&Ws[k][cg * 4];
            *(float4*)&w[4] = *(const float4*)&Ws[k][64 + cg * 4];
#pragma unroll
            for (int c = 0; c < 8; ++c) {
                acc[0][c] += a0 * w[c];
                acc[1][c] += a1 * w[c];
                acc[2][c] += a2 * w[c];
                acc[3][c] += a3 * w[c];
            }
        }
        __syncthreads();
    }
    // epilogue: + bias, store
    float bcol[8];
#pragma unroll
    for (int c = 0; c < 4; ++c) {
        bcol[c]     = bias[cg * 4 + c];
        bcol[c + 4] = bias[64 + cg * 4 + c];
    }
    int rbase = row0 + rg * 4;
#pragma unroll
    for (int i = 0; i < 4; ++i) {
        int grow = rbase + i;
        if (grow < N_NODES) {
            float4 o0, o1;
            o0.x = acc[i][0] + bcol[0]; o0.y = acc[i][1] + bcol[1];
            o0.z = acc[i][2] + bcol[2]; o0.w = acc[i][3] + bcol[3];
            o1.x = acc[i][4] + bcol[4]; o1.y = acc[i][5] + bcol[5];
            o1.z = acc[i][6] + bcol[6]; o1.w = acc[i][7] + bcol[7];
            *(float4*)(pre + (size_t)grow * D + cg * 4) = o0;
            *(float4*)(pre + (size_t)grow * D + 64 + cg * 4) = o1;
        }
    }
}

// ---------------- BN column stats: sums[j], sumsq[j] over N rows ----------------
__global__ void k_stats(const float* __restrict__ pre, float* __restrict__ sums,
                        float* __restrict__ sumsq) {
    int col  = threadIdx.x & 127;
    int rpar = threadIdx.x >> 7;   // 0 or 1
    float s = 0.f, ss = 0.f;
    for (int r = blockIdx.x * 2 + rpar; r < N_NODES; r += gridDim.x * 2) {
        float v = pre[(size_t)r * D + col];
        s += v; ss += v * v;
    }
    __shared__ float sm[256];
    sm[threadIdx.x] = s;
    __syncthreads();
    if (rpar == 0) s += sm[col + 128];
    __syncthreads();
    sm[threadIdx.x] = ss;
    __syncthreads();
    if (rpar == 0) {
        ss += sm[col + 128];
        atomicAdd(&sums[col], s);
        atomicAdd(&sumsq[col], ss);
    }
}

// ---------------- BN apply + ReLU (in place ok) ----------------
__global__ void k_bnrelu(const float* __restrict__ pre, const float* __restrict__ sums,
                         const float* __restrict__ sumsq, const float* __restrict__ gamma,
                         const float* __restrict__ beta, float* __restrict__ outbuf) {
    int idx = blockIdx.x * blockDim.x + threadIdx.x;   // float4 index
    const int total = N_NODES * D / 4;
    if (idx >= total) return;
    int col4 = (idx & 31) * 4;      // 32 float4 per row
    float4 v = ((const float4*)pre)[idx];
    float vv[4] = {v.x, v.y, v.z, v.w};
    float o[4];
    const float invN = 1.0f / (float)N_NODES;
#pragma unroll
    for (int c = 0; c < 4; ++c) {
        int j = col4 + c;
        float mu  = sums[j] * invN;
        float var = sumsq[j] * invN - mu * mu;
        float sc = gamma[j] * rsqrtf(var + BN_EPS);
        float sh = beta[j] - mu * sc;
        float x = vv[c] * sc + sh;
        o[c] = fmaxf(x, 0.f);
    }
    ((float4*)outbuf)[idx] = make_float4(o[0], o[1], o[2], o[3]);
}

// ---------------- MLP head + softmax: one wave per node ----------------
__global__ __launch_bounds__(256) void k_mlp(const float* __restrict__ h,
                                             const float* __restrict__ W1,
                                             const float* __restrict__ b1,
                                             const float* __restrict__ W2,
                                             const float* __restrict__ b2,
                                             float* __restrict__ out) {
    __shared__ float W1s[128 * 64];
    __shared__ float hrow[4][128];
    for (int idx = threadIdx.x; idx < 128 * 64 / 4; idx += 256)
        *(float4*)&W1s[idx * 4] = *(const float4*)&W1[idx * 4];
    __syncthreads();

    int wid = threadIdx.x >> 6, lane = threadIdx.x & 63;
    int gw = blockIdx.x * 4 + wid;
    int nw = gridDim.x * 4;
    float b2l0 = b2[0], b2l1 = b2[1];
    float w2a = W2[lane * 2], w2b = W2[lane * 2 + 1];
    float b1l = b1[lane];

    int iters = (N_NODES + nw - 1) / nw;
    for (int it = 0; it < iters; ++it) {
        int node = gw + it * nw;
        bool act = node < N_NODES;
        if (act) {
            float2 hv = ((const float2*)h)[(size_t)node * 64 + lane];
            hrow[wid][lane * 2]     = hv.x;
            hrow[wid][lane * 2 + 1] = hv.y;
        }
        __syncthreads();
        float z = b1l;
        if (act) {
#pragma unroll 8
            for (int k = 0; k < 128; ++k)
                z += hrow[wid][k] * W1s[k * 64 + lane];
        }
        z = fmaxf(z, 0.f);
        float pa = z * w2a, pb = z * w2b;
#pragma unroll
        for (int off = 32; off > 0; off >>= 1) {
            pa += __shfl_down(pa, off);
            pb += __shfl_down(pb, off);
        }
        if (lane == 0 && act) {
            float l0 = pa + b2l0, l1 = pb + b2l1;
            out[2 * node]     = l0;
            out[2 * node + 1] = l1;
            float m = fmaxf(l0, l1);
            float e0 = expf(l0 - m), e1 = expf(l1 - m);
            float s = 1.0f / (e0 + e1);
            out[2 * N_NODES + 2 * node]     = e0 * s;
            out[2 * N_NODES + 2 * node + 1] = e1 * s;
        }
        __syncthreads();
    }
}

extern "C" void kernel_launch(void* const* d_in, const int* in_sizes, int n_in,
                              void* d_out, int out_size, void* d_ws, size_t ws_size,
                              hipStream_t stream) {
    const float* x     = (const float*)d_in[0];
    const int*   ei    = (const int*)d_in[1];
    const int*   src   = ei;                 // edge_index[0]
    const int*   dst   = ei + N_EDGES;       // edge_index[1]
    const float* Wl    = (const float*)d_in[2];
    const float* Wr    = (const float*)d_in[3];
    const float* bl    = (const float*)d_in[4];
    const float* gamma = (const float*)d_in[5];
    const float* beta  = (const float*)d_in[6];
    const float* W1    = (const float*)d_in[7];
    const float* b1    = (const float*)d_in[8];
    const float* W2    = (const float*)d_in[9];
    const float* b2    = (const float*)d_in[10];
    float* out = (float*)d_out;

    char* ws = (char*)d_ws;
    size_t off = 0;
    auto alloc = [&](size_t bytes) -> void* {
        void* p = ws + off;
        off += (bytes + 255) & ~(size_t)255;
        return p;
    };
    float* Ha = (float*)alloc((size_t)N_NODES * D * 4);
    float* Hb = (float*)alloc((size_t)N_NODES * D * 4);
    float* Mb = (float*)alloc((size_t)N_NODES * D * 4);
    int* cnt         = (int*)alloc((size_t)N_NODES * 4);
    int* row_ptr     = (int*)alloc((size_t)(N_NODES + 1) * 4);
    int* row_fill    = (int*)alloc((size_t)N_NODES * 4);
    int* edge_sorted = (int*)alloc((size_t)N_EDGES * 4);
    float* sums      = (float*)alloc(256 * 4);   // sums[0:128], sumsq[128:256]
    float* sumsq = sums + 128;

    // --- build CSR (by dst), reused across the 3 layers ---
    hipMemsetAsync(cnt, 0, (size_t)N_NODES * 4, stream);
    k_hist<<<(N_EDGES + 255) / 256, 256, 0, stream>>>(dst, cnt);
    k_scan<<<1, 1024, 0, stream>>>(cnt, row_ptr);
    k_copy_int<<<(N_NODES + 255) / 256, 256, 0, stream>>>(row_ptr, row_fill, N_NODES);
    k_fill<<<(N_EDGES + 255) / 256, 256, 0, stream>>>(src, dst, row_fill, edge_sorted);

    // --- 3 SAGE layers ---
    const float* hcur = x;
    float* pre_t[3] = {Ha, Hb, Ha};
    for (int l = 0; l < NLAYERS; ++l) {
        k_agg<<<1024, 256, 0, stream>>>(hcur, edge_sorted, row_ptr, Mb);
        float* pre = pre_t[l];
        k_gemm<<<(N_NODES + 63) / 64, 256, 0, stream>>>(Mb, hcur, Wl + l * D * D,
                                                        Wr + l * D * D, bl + l * D, pre);
        hipMemsetAsync(sums, 0, 256 * 4, stream);
        k_stats<<<256, 256, 0, stream>>>(pre, sums, sumsq);
        k_bnrelu<<<(N_NODES * D / 4 + 255) / 256, 256, 0, stream>>>(
            pre, sums, sumsq, gamma + l * D, beta + l * D, pre);
        hcur = pre;
    }

    // --- MLP head + softmax ---
    k_mlp<<<512, 256, 0, stream>>>(hcur, W1, b1, W2, b2, out);
}

// Round 2
// 612.033 us; speedup vs baseline: 1.4556x; 1.4556x over previous
//
#include <hip/hip_runtime.h>
#include <math.h>

#define N_NODES 50000
#define N_EDGES 600000
#define D 128
#define NLAYERS 3
#define BN_EPS 1e-5f
#define NBLK ((N_NODES + 255) / 256)   // 196 scan blocks

// ---------------- CSR build ----------------
__global__ void k_hist(const int* __restrict__ dst, int* __restrict__ cnt) {
    int e = blockIdx.x * blockDim.x + threadIdx.x;
    if (e < N_EDGES) atomicAdd(&cnt[dst[e]], 1);
}

// phase 1: per-block exclusive scan of 256 cnt values; block total -> bsum
__global__ void k_local_scan(const int* __restrict__ cnt, int* __restrict__ row_ptr,
                             int* __restrict__ bsum) {
    __shared__ int sm[256];
    int tid = threadIdx.x;
    int i = blockIdx.x * 256 + tid;
    int v = (i < N_NODES) ? cnt[i] : 0;
    sm[tid] = v;
    __syncthreads();
    for (int off = 1; off < 256; off <<= 1) {
        int t = (tid >= off) ? sm[tid - off] : 0;
        __syncthreads();
        sm[tid] += t;
        __syncthreads();
    }
    int incl = sm[tid];
    if (i < N_NODES) row_ptr[i] = incl - v;      // local exclusive
    if (tid == 255) bsum[blockIdx.x] = incl;     // block total
}

// phase 2: single tiny block scans the NBLK block sums -> boff; writes total
__global__ void k_scan_bsums(const int* __restrict__ bsum, int* __restrict__ boff,
                             int* __restrict__ row_ptr) {
    __shared__ int sm[256];
    int tid = threadIdx.x;
    int v = (tid < NBLK) ? bsum[tid] : 0;
    sm[tid] = v;
    __syncthreads();
    for (int off = 1; off < 256; off <<= 1) {
        int t = (tid >= off) ? sm[tid - off] : 0;
        __syncthreads();
        sm[tid] += t;
        __syncthreads();
    }
    int incl = sm[tid];
    if (tid < NBLK) boff[tid] = incl - v;
    if (tid == 255) row_ptr[N_NODES] = incl;     // == N_EDGES
}

// phase 3: add block offsets; also produce row_fill copy
__global__ void k_add_off(int* __restrict__ row_ptr, const int* __restrict__ boff,
                          int* __restrict__ row_fill) {
    int i = blockIdx.x * 256 + threadIdx.x;
    if (i < N_NODES) {
        int v = row_ptr[i] + boff[i >> 8];
        row_ptr[i] = v;
        row_fill[i] = v;
    }
}

__global__ void k_fill(const int* __restrict__ src, const int* __restrict__ dst,
                       int* __restrict__ row_fill, int* __restrict__ edge_sorted) {
    int e = blockIdx.x * blockDim.x + threadIdx.x;
    if (e < N_EDGES) {
        int pos = atomicAdd(&row_fill[dst[e]], 1);
        edge_sorted[pos] = src[e];
    }
}

// ---------------- mean aggregation: one 32-lane group per node, float4/lane, ILP 4 ----
__global__ __launch_bounds__(256) void k_agg(const float* __restrict__ h,
                                             const int* __restrict__ edge_sorted,
                                             const int* __restrict__ row_ptr,
                                             float* __restrict__ meanbuf) {
    int node = blockIdx.x * 8 + (threadIdx.x >> 5);   // 8 groups per block
    int lane = threadIdx.x & 31;                      // 32 float4 = 128 floats per row
    if (node >= N_NODES) return;
    int beg = row_ptr[node], end = row_ptr[node + 1];
    const float4* hp = (const float4*)h;
    float ax = 0.f, ay = 0.f, az = 0.f, aw = 0.f;
    int j = beg;
    for (; j + 4 <= end; j += 4) {
        int s0 = edge_sorted[j + 0];
        int s1 = edge_sorted[j + 1];
        int s2 = edge_sorted[j + 2];
        int s3 = edge_sorted[j + 3];
        float4 v0 = hp[(size_t)s0 * 32 + lane];
        float4 v1 = hp[(size_t)s1 * 32 + lane];
        float4 v2 = hp[(size_t)s2 * 32 + lane];
        float4 v3 = hp[(size_t)s3 * 32 + lane];
        ax += v0.x + v1.x + v2.x + v3.x;
        ay += v0.y + v1.y + v2.y + v3.y;
        az += v0.z + v1.z + v2.z + v3.z;
        aw += v0.w + v1.w + v2.w + v3.w;
    }
    for (; j < end; ++j) {
        int s = edge_sorted[j];
        float4 v = hp[(size_t)s * 32 + lane];
        ax += v.x; ay += v.y; az += v.z; aw += v.w;
    }
    float inv = 1.0f / fmaxf((float)(end - beg), 1.0f);
    float4 o; o.x = ax * inv; o.y = ay * inv; o.z = az * inv; o.w = aw * inv;
    ((float4*)meanbuf)[(size_t)node * 32 + lane] = o;
}

// ---------------- fp32 GEMM: pre[n][j] = sum_k mean[n][k]*Wl[k][j] + h[n][k]*Wr[k][j] + bias[j]
__global__ __launch_bounds__(256) void k_gemm(const float* __restrict__ Amean,
                                              const float* __restrict__ Ah,
                                              const float* __restrict__ Wl,
                                              const float* __restrict__ Wr,
                                              const float* __restrict__ bias,
                                              float* __restrict__ pre) {
    __shared__ float As[64][36];   // +4 pad
    __shared__ float Ws[32][128];
    int tid = threadIdx.x;
    int rg = tid >> 4;     // 0..15 -> rows rg*4..rg*4+3
    int cg = tid & 15;     // 0..15 -> cols cg*4..+3 and 64+cg*4..+3
    int row0 = blockIdx.x * 64;

    float acc[4][8];
#pragma unroll
    for (int i = 0; i < 4; ++i)
#pragma unroll
        for (int c = 0; c < 8; ++c) acc[i][c] = 0.f;

    for (int kt = 0; kt < 8; ++kt) {
        const float* Asrc = (kt < 4) ? Amean : Ah;
        const float* Wsrc = (kt < 4) ? Wl : Wr;
        int kbase = (kt & 3) * 32;
#pragma unroll
        for (int t = 0; t < 2; ++t) {
            int idx = tid + t * 256;          // 0..511
            int r = idx >> 3;
            int kq = (idx & 7) << 2;
            int grow = row0 + r;
            float4 v = make_float4(0.f, 0.f, 0.f, 0.f);
            if (grow < N_NODES) v = *(const float4*)(Asrc + (size_t)grow * D + kbase + kq);
            *(float4*)&As[r][kq] = v;
        }
#pragma unroll
        for (int t = 0; t < 4; ++t) {
            int idx = tid + t * 256;          // 0..1023
            int r = idx >> 5;
            int c = (idx & 31) << 2;
            *(float4*)&Ws[r][c] = *(const float4*)(Wsrc + (size_t)(kbase + r) * D + c);
        }
        __syncthreads();
#pragma unroll
        for (int k = 0; k < 32; ++k) {
            float a0 = As[rg * 4 + 0][k];
            float a1 = As[rg * 4 + 1][k];
            float a2 = As[rg * 4 + 2][k];
            float a3 = As[rg * 4 + 3][k];
            float w[8];
            *(float4*)&w[0] = *(const float4*)&Ws[k][cg * 4];
            *(float4*)&w[4] = *(const float4*)&Ws[k][64 + cg * 4];
#pragma unroll
            for (int c = 0; c < 8; ++c) {
                acc[0][c] += a0 * w[c];
                acc[1][c] += a1 * w[c];
                acc[2][c] += a2 * w[c];
                acc[3][c] += a3 * w[c];
            }
        }
        __syncthreads();
    }
    float bcol[8];
#pragma unroll
    for (int c = 0; c < 4; ++c) {
        bcol[c]     = bias[cg * 4 + c];
        bcol[c + 4] = bias[64 + cg * 4 + c];
    }
    int rbase = row0 + rg * 4;
#pragma unroll
    for (int i = 0; i < 4; ++i) {
        int grow = rbase + i;
        if (grow < N_NODES) {
            float4 o0, o1;
            o0.x = acc[i][0] + bcol[0]; o0.y = acc[i][1] + bcol[1];
            o0.z = acc[i][2] + bcol[2]; o0.w = acc[i][3] + bcol[3];
            o1.x = acc[i][4] + bcol[4]; o1.y = acc[i][5] + bcol[5];
            o1.z = acc[i][6] + bcol[6]; o1.w = acc[i][7] + bcol[7];
            *(float4*)(pre + (size_t)grow * D + cg * 4) = o0;
            *(float4*)(pre + (size_t)grow * D + 64 + cg * 4) = o1;
        }
    }
}

// ---------------- BN column stats ----------------
__global__ void k_stats(const float* __restrict__ pre, float* __restrict__ sums,
                        float* __restrict__ sumsq) {
    int col  = threadIdx.x & 127;
    int rpar = threadIdx.x >> 7;
    float s = 0.f, ss = 0.f;
    for (int r = blockIdx.x * 2 + rpar; r < N_NODES; r += gridDim.x * 2) {
        float v = pre[(size_t)r * D + col];
        s += v; ss += v * v;
    }
    __shared__ float sm[256];
    sm[threadIdx.x] = s;
    __syncthreads();
    if (rpar == 0) s += sm[col + 128];
    __syncthreads();
    sm[threadIdx.x] = ss;
    __syncthreads();
    if (rpar == 0) {
        ss += sm[col + 128];
        atomicAdd(&sums[col], s);
        atomicAdd(&sumsq[col], ss);
    }
}

// ---------------- BN apply + ReLU ----------------
__global__ void k_bnrelu(const float* __restrict__ pre, const float* __restrict__ sums,
                         const float* __restrict__ sumsq, const float* __restrict__ gamma,
                         const float* __restrict__ beta, float* __restrict__ outbuf) {
    int idx = blockIdx.x * blockDim.x + threadIdx.x;
    const int total = N_NODES * D / 4;
    if (idx >= total) return;
    int col4 = (idx & 31) * 4;
    float4 v = ((const float4*)pre)[idx];
    float vv[4] = {v.x, v.y, v.z, v.w};
    float o[4];
    const float invN = 1.0f / (float)N_NODES;
#pragma unroll
    for (int c = 0; c < 4; ++c) {
        int j = col4 + c;
        float mu  = sums[j] * invN;
        float var = sumsq[j] * invN - mu * mu;
        float sc = gamma[j] * rsqrtf(var + BN_EPS);
        float sh = beta[j] - mu * sc;
        float x = vv[c] * sc + sh;
        o[c] = fmaxf(x, 0.f);
    }
    ((float4*)outbuf)[idx] = make_float4(o[0], o[1], o[2], o[3]);
}

// ---------------- MLP head + softmax: one wave per node ----------------
__global__ __launch_bounds__(256) void k_mlp(const float* __restrict__ h,
                                             const float* __restrict__ W1,
                                             const float* __restrict__ b1,
                                             const float* __restrict__ W2,
                                             const float* __restrict__ b2,
                                             float* __restrict__ out) {
    __shared__ float W1s[128 * 64];
    __shared__ float hrow[4][128];
    for (int idx = threadIdx.x; idx < 128 * 64 / 4; idx += 256)
        *(float4*)&W1s[idx * 4] = *(const float4*)&W1[idx * 4];
    __syncthreads();

    int wid = threadIdx.x >> 6, lane = threadIdx.x & 63;
    int gw = blockIdx.x * 4 + wid;
    int nw = gridDim.x * 4;
    float b2l0 = b2[0], b2l1 = b2[1];
    float w2a = W2[lane * 2], w2b = W2[lane * 2 + 1];
    float b1l = b1[lane];

    int iters = (N_NODES + nw - 1) / nw;
    for (int it = 0; it < iters; ++it) {
        int node = gw + it * nw;
        bool act = node < N_NODES;
        if (act) {
            float2 hv = ((const float2*)h)[(size_t)node * 64 + lane];
            hrow[wid][lane * 2]     = hv.x;
            hrow[wid][lane * 2 + 1] = hv.y;
        }
        __syncthreads();
        float z = b1l;
        if (act) {
#pragma unroll 8
            for (int k = 0; k < 128; ++k)
                z += hrow[wid][k] * W1s[k * 64 + lane];
        }
        z = fmaxf(z, 0.f);
        float pa = z * w2a, pb = z * w2b;
#pragma unroll
        for (int off = 32; off > 0; off >>= 1) {
            pa += __shfl_down(pa, off);
            pb += __shfl_down(pb, off);
        }
        if (lane == 0 && act) {
            float l0 = pa + b2l0, l1 = pb + b2l1;
            out[2 * node]     = l0;
            out[2 * node + 1] = l1;
            float m = fmaxf(l0, l1);
            float e0 = expf(l0 - m), e1 = expf(l1 - m);
            float s = 1.0f / (e0 + e1);
            out[2 * N_NODES + 2 * node]     = e0 * s;
            out[2 * N_NODES + 2 * node + 1] = e1 * s;
        }
        __syncthreads();
    }
}

extern "C" void kernel_launch(void* const* d_in, const int* in_sizes, int n_in,
                              void* d_out, int out_size, void* d_ws, size_t ws_size,
                              hipStream_t stream) {
    const float* x     = (const float*)d_in[0];
    const int*   ei    = (const int*)d_in[1];
    const int*   src   = ei;
    const int*   dst   = ei + N_EDGES;
    const float* Wl    = (const float*)d_in[2];
    const float* Wr    = (const float*)d_in[3];
    const float* bl    = (const float*)d_in[4];
    const float* gamma = (const float*)d_in[5];
    const float* beta  = (const float*)d_in[6];
    const float* W1    = (const float*)d_in[7];
    const float* b1    = (const float*)d_in[8];
    const float* W2    = (const float*)d_in[9];
    const float* b2    = (const float*)d_in[10];
    float* out = (float*)d_out;

    char* ws = (char*)d_ws;
    size_t off = 0;
    auto alloc = [&](size_t bytes) -> void* {
        void* p = ws + off;
        off += (bytes + 255) & ~(size_t)255;
        return p;
    };
    float* Ha = (float*)alloc((size_t)N_NODES * D * 4);
    float* Hb = (float*)alloc((size_t)N_NODES * D * 4);
    float* Mb = (float*)alloc((size_t)N_NODES * D * 4);
    int* cnt         = (int*)alloc((size_t)N_NODES * 4);
    int* row_ptr     = (int*)alloc((size_t)(N_NODES + 1) * 4);
    int* row_fill    = (int*)alloc((size_t)N_NODES * 4);
    int* edge_sorted = (int*)alloc((size_t)N_EDGES * 4);
    int* bsum        = (int*)alloc((size_t)NBLK * 4);
    int* boff        = (int*)alloc((size_t)NBLK * 4);
    float* sums      = (float*)alloc(256 * 4);
    float* sumsq = sums + 128;

    // --- build CSR (by dst), reused across the 3 layers ---
    hipMemsetAsync(cnt, 0, (size_t)N_NODES * 4, stream);
    k_hist<<<(N_EDGES + 255) / 256, 256, 0, stream>>>(dst, cnt);
    k_local_scan<<<NBLK, 256, 0, stream>>>(cnt, row_ptr, bsum);
    k_scan_bsums<<<1, 256, 0, stream>>>(bsum, boff, row_ptr);
    k_add_off<<<NBLK, 256, 0, stream>>>(row_ptr, boff, row_fill);
    k_fill<<<(N_EDGES + 255) / 256, 256, 0, stream>>>(src, dst, row_fill, edge_sorted);

    // --- 3 SAGE layers ---
    const float* hcur = x;
    float* pre_t[3] = {Ha, Hb, Ha};
    for (int l = 0; l < NLAYERS; ++l) {
        k_agg<<<(N_NODES + 7) / 8, 256, 0, stream>>>(hcur, edge_sorted, row_ptr, Mb);
        float* pre = pre_t[l];
        k_gemm<<<(N_NODES + 63) / 64, 256, 0, stream>>>(Mb, hcur, Wl + l * D * D,
                                                        Wr + l * D * D, bl + l * D, pre);
        hipMemsetAsync(sums, 0, 256 * 4, stream);
        k_stats<<<256, 256, 0, stream>>>(pre, sums, sumsq);
        k_bnrelu<<<(N_NODES * D / 4 + 255) / 256, 256, 0, stream>>>(
            pre, sums, sumsq, gamma + l * D, beta + l * D, pre);
        hcur = pre;
    }

    // --- MLP head + softmax ---
    k_mlp<<<512, 256, 0, stream>>>(hcur, W1, b1, W2, b2, out);
}

// Round 3
// 498.725 us; speedup vs baseline: 1.7863x; 1.2272x over previous
//
#include <hip/hip_runtime.h>
#include <math.h>

#define N_NODES 50000
#define N_EDGES 600000
#define D 128
#define NLAYERS 3
#define BN_EPS 1e-5f
#define NBLK ((N_NODES + 255) / 256)       // 196 scan blocks
#define GBLK ((N_NODES + 63) / 64)         // 782 gemm blocks

typedef short short8 __attribute__((ext_vector_type(8)));   // 8 bf16 (4 VGPRs)
typedef float f32x4 __attribute__((ext_vector_type(4)));

__device__ __forceinline__ float b2f(unsigned short u) {
    return __uint_as_float(((unsigned int)u) << 16);
}
__device__ __forceinline__ unsigned short f2b(float f) {  // RNE
    unsigned int b = __float_as_uint(f);
    return (unsigned short)((b + 0x7fffu + ((b >> 16) & 1u)) >> 16);
}

// ---------------- converts ----------------
__global__ void k_cvt_x(const float* __restrict__ x, unsigned short* __restrict__ xb) {
    int idx = blockIdx.x * 256 + threadIdx.x;       // float4 granule
    if (idx >= N_NODES * D / 4) return;
    float4 v = ((const float4*)x)[idx];
    ushort4 o;
    o.x = f2b(v.x); o.y = f2b(v.y); o.z = f2b(v.z); o.w = f2b(v.w);
    ((ushort4*)xb)[idx] = o;
}

// Wt[l][c][k]: k<128 -> Wl[l][k][c], k>=128 -> Wr[l][k-128][c]
__global__ void k_cvt_w(const float* __restrict__ Wl, const float* __restrict__ Wr,
                        unsigned short* __restrict__ Wt) {
    int idx = blockIdx.x * 256 + threadIdx.x;       // 3*128*256 total
    if (idx >= NLAYERS * 128 * 256) return;
    int l = idx >> 15;
    int rem = idx & 32767;
    int c = rem >> 8;
    int k = rem & 255;
    float v = (k < 128) ? Wl[l * 16384 + k * 128 + c] : Wr[l * 16384 + (k - 128) * 128 + c];
    Wt[idx] = f2b(v);
}

// ---------------- CSR build ----------------
__global__ void k_hist(const int* __restrict__ dst, int* __restrict__ cnt) {
    int e = blockIdx.x * blockDim.x + threadIdx.x;
    if (e < N_EDGES) atomicAdd(&cnt[dst[e]], 1);
}

__global__ void k_local_scan(const int* __restrict__ cnt, int* __restrict__ row_ptr,
                             int* __restrict__ bsum) {
    __shared__ int sm[256];
    int tid = threadIdx.x;
    int i = blockIdx.x * 256 + tid;
    int v = (i < N_NODES) ? cnt[i] : 0;
    sm[tid] = v;
    __syncthreads();
    for (int off = 1; off < 256; off <<= 1) {
        int t = (tid >= off) ? sm[tid - off] : 0;
        __syncthreads();
        sm[tid] += t;
        __syncthreads();
    }
    int incl = sm[tid];
    if (i < N_NODES) row_ptr[i] = incl - v;
    if (tid == 255) bsum[blockIdx.x] = incl;
}

__global__ void k_scan_bsums(const int* __restrict__ bsum, int* __restrict__ boff,
                             int* __restrict__ row_ptr) {
    __shared__ int sm[256];
    int tid = threadIdx.x;
    int v = (tid < NBLK) ? bsum[tid] : 0;
    sm[tid] = v;
    __syncthreads();
    for (int off = 1; off < 256; off <<= 1) {
        int t = (tid >= off) ? sm[tid - off] : 0;
        __syncthreads();
        sm[tid] += t;
        __syncthreads();
    }
    int incl = sm[tid];
    if (tid < NBLK) boff[tid] = incl - v;
    if (tid == 255) row_ptr[N_NODES] = incl;
}

__global__ void k_add_off(int* __restrict__ row_ptr, const int* __restrict__ boff,
                          int* __restrict__ row_fill) {
    int i = blockIdx.x * 256 + threadIdx.x;
    if (i < N_NODES) {
        int v = row_ptr[i] + boff[i >> 8];
        row_ptr[i] = v;
        row_fill[i] = v;
    }
}

__global__ void k_fill(const int* __restrict__ src, const int* __restrict__ dst,
                       int* __restrict__ row_fill, int* __restrict__ edge_sorted) {
    int e = blockIdx.x * blockDim.x + threadIdx.x;
    if (e < N_EDGES) {
        int pos = atomicAdd(&row_fill[dst[e]], 1);
        edge_sorted[pos] = src[e];
    }
}

// ---------------- mean aggregation: 16 lanes per node (bf16 rows), ILP 4 ----------------
__global__ __launch_bounds__(256) void k_agg(const unsigned short* __restrict__ h,
                                             const int* __restrict__ edge_sorted,
                                             const int* __restrict__ row_ptr,
                                             unsigned short* __restrict__ meanbuf) {
    int node = blockIdx.x * 16 + (threadIdx.x >> 4);   // 3125 blocks exactly
    int lane = threadIdx.x & 15;                       // 16 x short8 = 128 bf16 per row
    int beg = row_ptr[node], end = row_ptr[node + 1];
    const short8* hp = (const short8*)h;
    float a[8];
#pragma unroll
    for (int i = 0; i < 8; ++i) a[i] = 0.f;
    int j = beg;
    for (; j + 4 <= end; j += 4) {
        int s0 = edge_sorted[j + 0];
        int s1 = edge_sorted[j + 1];
        int s2 = edge_sorted[j + 2];
        int s3 = edge_sorted[j + 3];
        short8 v0 = hp[(size_t)s0 * 16 + lane];
        short8 v1 = hp[(size_t)s1 * 16 + lane];
        short8 v2 = hp[(size_t)s2 * 16 + lane];
        short8 v3 = hp[(size_t)s3 * 16 + lane];
#pragma unroll
        for (int i = 0; i < 8; ++i) {
            a[i] += b2f((unsigned short)v0[i]) + b2f((unsigned short)v1[i]) +
                    b2f((unsigned short)v2[i]) + b2f((unsigned short)v3[i]);
        }
    }
    for (; j < end; ++j) {
        int s = edge_sorted[j];
        short8 v = hp[(size_t)s * 16 + lane];
#pragma unroll
        for (int i = 0; i < 8; ++i) a[i] += b2f((unsigned short)v[i]);
    }
    float inv = 1.0f / fmaxf((float)(end - beg), 1.0f);
    short8 o;
#pragma unroll
    for (int i = 0; i < 8; ++i) o[i] = (short)f2b(a[i] * inv);
    ((short8*)meanbuf)[(size_t)node * 16 + lane] = o;
}

// ---------------- bf16 MFMA GEMM + fused BN partial stats ----------------
// pre[n][j] = sum_k mean[n][k]*Wl[k][j] + h[n][k]*Wr[k][j] + bias[j]  (fp32 out)
// block = 256 thr = 4 waves; wave -> 16 rows x 128 cols; mfma 16x16x32 bf16
__global__ __launch_bounds__(256) void k_gemm_mfma(const unsigned short* __restrict__ Am,
                                                   const unsigned short* __restrict__ Ah,
                                                   const unsigned short* __restrict__ Wt,
                                                   const float* __restrict__ bias,
                                                   float* __restrict__ pre,
                                                   float* __restrict__ partial) {
    __shared__ float red[4][256];
    int wave = threadIdx.x >> 6;
    int lane = threadIdx.x & 63;
    int col = lane & 15;
    int quad = lane >> 4;
    int row_base = blockIdx.x * 64 + wave * 16;
    bool valid = row_base < N_NODES;       // N % 16 == 0 -> all-or-nothing per wave

    f32x4 acc[8];
#pragma unroll
    for (int t = 0; t < 8; ++t) acc[t] = (f32x4){0.f, 0.f, 0.f, 0.f};

    if (valid) {
        int arow = row_base + col;
#pragma unroll
        for (int kk = 0; kk < 8; ++kk) {
            const unsigned short* Aptr = (kk < 4) ? Am : Ah;
            int kofs = (kk & 3) * 32 + quad * 8;
            short8 a = *(const short8*)(Aptr + (size_t)arow * D + kofs);
#pragma unroll
            for (int t = 0; t < 8; ++t) {
                short8 b = *(const short8*)(Wt + (size_t)(t * 16 + col) * 256 + kk * 32 + quad * 8);
                acc[t] = __builtin_amdgcn_mfma_f32_16x16x32_bf16(a, b, acc[t], 0, 0, 0);
            }
        }
    }

    // epilogue: bias, store pre (fp32), per-wave column stats
#pragma unroll
    for (int t = 0; t < 8; ++t) {
        float s = 0.f, ss = 0.f;
        if (valid) {
            float bc = bias[t * 16 + col];
#pragma unroll
            for (int r = 0; r < 4; ++r) {
                float v = acc[t][r] + bc;
                pre[(size_t)(row_base + quad * 4 + r) * D + t * 16 + col] = v;
                s += v;
                ss += v * v;
            }
        }
        // reduce across the 4 quads (lanes sharing col)
        s += __shfl_xor(s, 16);  ss += __shfl_xor(ss, 16);
        s += __shfl_xor(s, 32);  ss += __shfl_xor(ss, 32);
        if (quad == 0) {
            red[wave][t * 16 + col] = s;
            red[wave][128 + t * 16 + col] = ss;
        }
    }
    __syncthreads();
    int tid = threadIdx.x;
    partial[(size_t)blockIdx.x * 256 + tid] =
        red[0][tid] + red[1][tid] + red[2][tid] + red[3][tid];
}

// ---------------- reduce partials -> sums[128], sumsq[128] ----------------
__global__ void k_reduce_stats(const float* __restrict__ partial, float* __restrict__ sums) {
    int t = threadIdx.x;           // 0..255
    float acc = 0.f;
    for (int b = blockIdx.x; b < GBLK; b += gridDim.x)
        acc += partial[(size_t)b * 256 + t];
    atomicAdd(&sums[t], acc);
}

// ---------------- BN apply + ReLU: fp32 pre -> bf16 h ----------------
__global__ void k_bnrelu(const float* __restrict__ pre, const float* __restrict__ sums,
                         const float* __restrict__ sumsq, const float* __restrict__ gamma,
                         const float* __restrict__ beta, unsigned short* __restrict__ outbuf) {
    int idx = blockIdx.x * blockDim.x + threadIdx.x;
    const int total = N_NODES * D / 4;
    if (idx >= total) return;
    int col4 = (idx & 31) * 4;
    float4 v = ((const float4*)pre)[idx];
    float vv[4] = {v.x, v.y, v.z, v.w};
    unsigned short o[4];
    const float invN = 1.0f / (float)N_NODES;
#pragma unroll
    for (int c = 0; c < 4; ++c) {
        int j = col4 + c;
        float mu  = sums[j] * invN;
        float var = sumsq[j] * invN - mu * mu;
        float sc = gamma[j] * rsqrtf(var + BN_EPS);
        float sh = beta[j] - mu * sc;
        float x = vv[c] * sc + sh;
        o[c] = f2b(fmaxf(x, 0.f));
    }
    ushort4 ov; ov.x = o[0]; ov.y = o[1]; ov.z = o[2]; ov.w = o[3];
    ((ushort4*)outbuf)[idx] = ov;
}

// ---------------- MLP head + softmax: one wave per node, bf16 input ----------------
__global__ __launch_bounds__(256) void k_mlp(const unsigned short* __restrict__ h,
                                             const float* __restrict__ W1,
                                             const float* __restrict__ b1,
                                             const float* __restrict__ W2,
                                             const float* __restrict__ b2,
                                             float* __restrict__ out) {
    __shared__ float W1s[128 * 64];
    __shared__ float hrow[4][128];
    for (int idx = threadIdx.x; idx < 128 * 64 / 4; idx += 256)
        *(float4*)&W1s[idx * 4] = *(const float4*)&W1[idx * 4];
    __syncthreads();

    int wid = threadIdx.x >> 6, lane = threadIdx.x & 63;
    int gw = blockIdx.x * 4 + wid;
    int nw = gridDim.x * 4;
    float b2l0 = b2[0], b2l1 = b2[1];
    float w2a = W2[lane * 2], w2b = W2[lane * 2 + 1];
    float b1l = b1[lane];

    int iters = (N_NODES + nw - 1) / nw;
    for (int it = 0; it < iters; ++it) {
        int node = gw + it * nw;
        bool act = node < N_NODES;
        if (act) {
            ushort2 hv = ((const ushort2*)h)[(size_t)node * 64 + lane];
            hrow[wid][lane * 2]     = b2f(hv.x);
            hrow[wid][lane * 2 + 1] = b2f(hv.y);
        }
        __syncthreads();
        float z = b1l;
        if (act) {
#pragma unroll 8
            for (int k = 0; k < 128; ++k)
                z += hrow[wid][k] * W1s[k * 64 + lane];
        }
        z = fmaxf(z, 0.f);
        float pa = z * w2a, pb = z * w2b;
#pragma unroll
        for (int off = 32; off > 0; off >>= 1) {
            pa += __shfl_down(pa, off);
            pb += __shfl_down(pb, off);
        }
        if (lane == 0 && act) {
            float l0 = pa + b2l0, l1 = pb + b2l1;
            out[2 * node]     = l0;
            out[2 * node + 1] = l1;
            float m = fmaxf(l0, l1);
            float e0 = expf(l0 - m), e1 = expf(l1 - m);
            float s = 1.0f / (e0 + e1);
            out[2 * N_NODES + 2 * node]     = e0 * s;
            out[2 * N_NODES + 2 * node + 1] = e1 * s;
        }
        __syncthreads();
    }
}

extern "C" void kernel_launch(void* const* d_in, const int* in_sizes, int n_in,
                              void* d_out, int out_size, void* d_ws, size_t ws_size,
                              hipStream_t stream) {
    const float* x     = (const float*)d_in[0];
    const int*   ei    = (const int*)d_in[1];
    const int*   src   = ei;
    const int*   dst   = ei + N_EDGES;
    const float* Wl    = (const float*)d_in[2];
    const float* Wr    = (const float*)d_in[3];
    const float* bl    = (const float*)d_in[4];
    const float* gamma = (const float*)d_in[5];
    const float* beta  = (const float*)d_in[6];
    const float* W1    = (const float*)d_in[7];
    const float* b1    = (const float*)d_in[8];
    const float* W2    = (const float*)d_in[9];
    const float* b2    = (const float*)d_in[10];
    float* out = (float*)d_out;

    char* ws = (char*)d_ws;
    size_t off = 0;
    auto alloc = [&](size_t bytes) -> void* {
        void* p = ws + off;
        off += (bytes + 255) & ~(size_t)255;
        return p;
    };
    unsigned short* xb   = (unsigned short*)alloc((size_t)N_NODES * D * 2);  // also reused as 2nd h buf
    unsigned short* Ha   = (unsigned short*)alloc((size_t)N_NODES * D * 2);
    unsigned short* Mb   = (unsigned short*)alloc((size_t)N_NODES * D * 2);
    float* pre           = (float*)alloc((size_t)N_NODES * D * 4);
    unsigned short* Wtb  = (unsigned short*)alloc((size_t)NLAYERS * 128 * 256 * 2);
    float* partial       = (float*)alloc((size_t)GBLK * 256 * 4);
    int* cnt             = (int*)alloc((size_t)N_NODES * 4);
    int* row_ptr         = (int*)alloc((size_t)(N_NODES + 1) * 4);
    int* row_fill        = (int*)alloc((size_t)N_NODES * 4);
    int* edge_sorted     = (int*)alloc((size_t)N_EDGES * 4);
    int* bsum            = (int*)alloc((size_t)NBLK * 4);
    int* boff            = (int*)alloc((size_t)NBLK * 4);
    float* sums          = (float*)alloc(256 * 4);
    float* sumsq = sums + 128;

    // --- converts ---
    k_cvt_x<<<(N_NODES * D / 4 + 255) / 256, 256, 0, stream>>>(x, xb);
    k_cvt_w<<<(NLAYERS * 128 * 256 + 255) / 256, 256, 0, stream>>>(Wl, Wr, Wtb);

    // --- build CSR (by dst), reused across the 3 layers ---
    hipMemsetAsync(cnt, 0, (size_t)N_NODES * 4, stream);
    k_hist<<<(N_EDGES + 255) / 256, 256, 0, stream>>>(dst, cnt);
    k_local_scan<<<NBLK, 256, 0, stream>>>(cnt, row_ptr, bsum);
    k_scan_bsums<<<1, 256, 0, stream>>>(bsum, boff, row_ptr);
    k_add_off<<<NBLK, 256, 0, stream>>>(row_ptr, boff, row_fill);
    k_fill<<<(N_EDGES + 255) / 256, 256, 0, stream>>>(src, dst, row_fill, edge_sorted);

    // --- 3 SAGE layers (h buffers ping-pong: xb -> Ha -> xb -> Ha) ---
    const unsigned short* hcur = xb;
    unsigned short* hout[3] = {Ha, xb, Ha};
    for (int l = 0; l < NLAYERS; ++l) {
        k_agg<<<N_NODES / 16, 256, 0, stream>>>(hcur, edge_sorted, row_ptr, Mb);
        hipMemsetAsync(sums, 0, 256 * 4, stream);
        k_gemm_mfma<<<GBLK, 256, 0, stream>>>(Mb, hcur, Wtb + (size_t)l * 32768,
                                              bl + l * D, pre, partial);
        k_reduce_stats<<<8, 256, 0, stream>>>(partial, sums);
        k_bnrelu<<<(N_NODES * D / 4 + 255) / 256, 256, 0, stream>>>(
            pre, sums, sumsq, gamma + l * D, beta + l * D, hout[l]);
        hcur = hout[l];
    }

    // --- MLP head + softmax ---
    k_mlp<<<512, 256, 0, stream>>>(hcur, W1, b1, W2, b2, out);
}

// Round 4
// 426.273 us; speedup vs baseline: 2.0899x; 1.1700x over previous
//
#include <hip/hip_runtime.h>
#include <math.h>

#define N_NODES 50000
#define N_EDGES 600000
#define D 128
#define NLAYERS 3
#define BN_EPS 1e-5f
#define NBLK ((N_NODES + 255) / 256)       // 196 scan blocks
#define GBLK ((N_NODES + 63) / 64)         // 782 gemm blocks
#define NW (NLAYERS * 128 * 256)           // Wt elements

typedef short short8 __attribute__((ext_vector_type(8)));   // 8 bf16 (4 VGPRs)
typedef float f32x4 __attribute__((ext_vector_type(4)));

__device__ __forceinline__ float b2f(unsigned short u) {
    return __uint_as_float(((unsigned int)u) << 16);
}
__device__ __forceinline__ unsigned short f2b(float f) {  // RNE
    unsigned int b = __float_as_uint(f);
    return (unsigned short)((b + 0x7fffu + ((b >> 16) & 1u)) >> 16);
}

// ---------------- converts ----------------
__global__ void k_cvt_x(const float* __restrict__ x, unsigned short* __restrict__ xb) {
    int idx = blockIdx.x * 256 + threadIdx.x;       // float4 granule
    if (idx >= N_NODES * D / 4) return;
    float4 v = ((const float4*)x)[idx];
    ushort4 o;
    o.x = f2b(v.x); o.y = f2b(v.y); o.z = f2b(v.z); o.w = f2b(v.w);
    ((ushort4*)xb)[idx] = o;
}

// Wt[l][c][k]: k<128 -> Wl[l][k][c], k>=128 -> Wr[l][k-128][c];  W1t[c][k] = W1[k][c]
__global__ void k_cvt_weights(const float* __restrict__ Wl, const float* __restrict__ Wr,
                              const float* __restrict__ W1, unsigned short* __restrict__ Wt,
                              unsigned short* __restrict__ W1t) {
    int idx = blockIdx.x * 256 + threadIdx.x;
    if (idx < NW) {
        int l = idx >> 15;
        int rem = idx & 32767;
        int c = rem >> 8;
        int k = rem & 255;
        float v = (k < 128) ? Wl[l * 16384 + k * 128 + c]
                            : Wr[l * 16384 + (k - 128) * 128 + c];
        Wt[idx] = f2b(v);
    } else {
        int i = idx - NW;
        if (i < 64 * 128) {
            int c = i >> 7;
            int k = i & 127;
            W1t[i] = f2b(W1[k * 64 + c]);
        }
    }
}

// ---------------- CSR build ----------------
__global__ void k_hist(const int* __restrict__ dst, int* __restrict__ cnt) {
    int e = blockIdx.x * blockDim.x + threadIdx.x;
    if (e < N_EDGES) atomicAdd(&cnt[dst[e]], 1);
}

__global__ void k_local_scan(const int* __restrict__ cnt, int* __restrict__ row_ptr,
                             int* __restrict__ bsum) {
    __shared__ int sm[256];
    int tid = threadIdx.x;
    int i = blockIdx.x * 256 + tid;
    int v = (i < N_NODES) ? cnt[i] : 0;
    sm[tid] = v;
    __syncthreads();
    for (int off = 1; off < 256; off <<= 1) {
        int t = (tid >= off) ? sm[tid - off] : 0;
        __syncthreads();
        sm[tid] += t;
        __syncthreads();
    }
    int incl = sm[tid];
    if (i < N_NODES) row_ptr[i] = incl - v;
    if (tid == 255) bsum[blockIdx.x] = incl;
}

__global__ void k_scan_bsums(const int* __restrict__ bsum, int* __restrict__ boff,
                             int* __restrict__ row_ptr) {
    __shared__ int sm[256];
    int tid = threadIdx.x;
    int v = (tid < NBLK) ? bsum[tid] : 0;
    sm[tid] = v;
    __syncthreads();
    for (int off = 1; off < 256; off <<= 1) {
        int t = (tid >= off) ? sm[tid - off] : 0;
        __syncthreads();
        sm[tid] += t;
        __syncthreads();
    }
    int incl = sm[tid];
    if (tid < NBLK) boff[tid] = incl - v;
    if (tid == 255) row_ptr[N_NODES] = incl;
}

__global__ void k_add_off(int* __restrict__ row_ptr, const int* __restrict__ boff,
                          int* __restrict__ row_fill) {
    int i = blockIdx.x * 256 + threadIdx.x;
    if (i < N_NODES) {
        int v = row_ptr[i] + boff[i >> 8];
        row_ptr[i] = v;
        row_fill[i] = v;
    }
}

__global__ void k_fill(const int* __restrict__ src, const int* __restrict__ dst,
                       int* __restrict__ row_fill, int* __restrict__ edge_sorted) {
    int e = blockIdx.x * blockDim.x + threadIdx.x;
    if (e < N_EDGES) {
        int pos = atomicAdd(&row_fill[dst[e]], 1);
        edge_sorted[pos] = src[e];
    }
}

// ---------------- mean aggregation: 16 lanes per node, masked ILP-4 gather ----------------
__global__ __launch_bounds__(256) void k_agg(const unsigned short* __restrict__ h,
                                             const int* __restrict__ edge_sorted,
                                             const int* __restrict__ row_ptr,
                                             unsigned short* __restrict__ meanbuf) {
    int node = blockIdx.x * 16 + (threadIdx.x >> 4);   // 3125 blocks exactly
    int lane = threadIdx.x & 15;                       // 16 x short8 = 128 bf16 per row
    int beg = row_ptr[node], end = row_ptr[node + 1];
    const short8* hp = (const short8*)h;
    float a[8];
#pragma unroll
    for (int i = 0; i < 8; ++i) a[i] = 0.f;
    int e1 = end - 1;
    for (int j = beg; j < end; j += 4) {
        int j1 = j + 1, j2 = j + 2, j3 = j + 3;
        int i1 = (j1 <= e1) ? j1 : e1;
        int i2 = (j2 <= e1) ? j2 : e1;
        int i3 = (j3 <= e1) ? j3 : e1;
        int s0 = edge_sorted[j];
        int s1 = edge_sorted[i1];
        int s2 = edge_sorted[i2];
        int s3 = edge_sorted[i3];
        short8 v0 = hp[(size_t)s0 * 16 + lane];
        short8 v1 = hp[(size_t)s1 * 16 + lane];
        short8 v2 = hp[(size_t)s2 * 16 + lane];
        short8 v3 = hp[(size_t)s3 * 16 + lane];
        float m1 = (j1 < end) ? 1.f : 0.f;
        float m2 = (j2 < end) ? 1.f : 0.f;
        float m3 = (j3 < end) ? 1.f : 0.f;
#pragma unroll
        for (int i = 0; i < 8; ++i) {
            float t = a[i] + b2f((unsigned short)v0[i]);
            t = fmaf(m1, b2f((unsigned short)v1[i]), t);
            t = fmaf(m2, b2f((unsigned short)v2[i]), t);
            t = fmaf(m3, b2f((unsigned short)v3[i]), t);
            a[i] = t;
        }
    }
    float inv = 1.0f / fmaxf((float)(end - beg), 1.0f);
    short8 o;
#pragma unroll
    for (int i = 0; i < 8; ++i) o[i] = (short)f2b(a[i] * inv);
    ((short8*)meanbuf)[(size_t)node * 16 + lane] = o;
}

// ---------------- bf16 MFMA GEMM + fused BN partial stats ----------------
__global__ __launch_bounds__(256) void k_gemm_mfma(const unsigned short* __restrict__ Am,
                                                   const unsigned short* __restrict__ Ah,
                                                   const unsigned short* __restrict__ Wt,
                                                   const float* __restrict__ bias,
                                                   float* __restrict__ pre,
                                                   float* __restrict__ partial) {
    __shared__ float red[4][256];
    int wave = threadIdx.x >> 6;
    int lane = threadIdx.x & 63;
    int col = lane & 15;
    int quad = lane >> 4;
    int row_base = blockIdx.x * 64 + wave * 16;
    bool valid = row_base < N_NODES;       // N % 16 == 0 -> all-or-nothing per wave

    f32x4 acc[8];
#pragma unroll
    for (int t = 0; t < 8; ++t) acc[t] = (f32x4){0.f, 0.f, 0.f, 0.f};

    if (valid) {
        int arow = row_base + col;
#pragma unroll
        for (int kk = 0; kk < 8; ++kk) {
            const unsigned short* Aptr = (kk < 4) ? Am : Ah;
            int kofs = (kk & 3) * 32 + quad * 8;
            short8 a = *(const short8*)(Aptr + (size_t)arow * D + kofs);
#pragma unroll
            for (int t = 0; t < 8; ++t) {
                short8 b = *(const short8*)(Wt + (size_t)(t * 16 + col) * 256 + kk * 32 + quad * 8);
                acc[t] = __builtin_amdgcn_mfma_f32_16x16x32_bf16(a, b, acc[t], 0, 0, 0);
            }
        }
    }

#pragma unroll
    for (int t = 0; t < 8; ++t) {
        float s = 0.f, ss = 0.f;
        if (valid) {
            float bc = bias[t * 16 + col];
#pragma unroll
            for (int r = 0; r < 4; ++r) {
                float v = acc[t][r] + bc;
                pre[(size_t)(row_base + quad * 4 + r) * D + t * 16 + col] = v;
                s += v;
                ss += v * v;
            }
        }
        s += __shfl_xor(s, 16);  ss += __shfl_xor(ss, 16);
        s += __shfl_xor(s, 32);  ss += __shfl_xor(ss, 32);
        if (quad == 0) {
            red[wave][t * 16 + col] = s;
            red[wave][128 + t * 16 + col] = ss;
        }
    }
    __syncthreads();
    int tid = threadIdx.x;
    partial[(size_t)blockIdx.x * 256 + tid] =
        red[0][tid] + red[1][tid] + red[2][tid] + red[3][tid];
}

// ---------------- reduce partials -> sums[128], sumsq[128] (single block, no memset) ----
__global__ void k_reduce_stats(const float* __restrict__ partial, float* __restrict__ sums) {
    int t = threadIdx.x;           // 0..255
    float a0 = 0.f, a1 = 0.f, a2 = 0.f, a3 = 0.f;
    int b = 0;
    for (; b + 4 <= GBLK; b += 4) {
        a0 += partial[(size_t)(b + 0) * 256 + t];
        a1 += partial[(size_t)(b + 1) * 256 + t];
        a2 += partial[(size_t)(b + 2) * 256 + t];
        a3 += partial[(size_t)(b + 3) * 256 + t];
    }
    for (; b < GBLK; ++b) a0 += partial[(size_t)b * 256 + t];
    sums[t] = (a0 + a1) + (a2 + a3);
}

// ---------------- BN apply + ReLU: fp32 pre -> bf16 h ----------------
__global__ void k_bnrelu(const float* __restrict__ pre, const float* __restrict__ sums,
                         const float* __restrict__ sumsq, const float* __restrict__ gamma,
                         const float* __restrict__ beta, unsigned short* __restrict__ outbuf) {
    int idx = blockIdx.x * blockDim.x + threadIdx.x;
    const int total = N_NODES * D / 4;
    if (idx >= total) return;
    int col4 = (idx & 31) * 4;
    float4 v = ((const float4*)pre)[idx];
    float vv[4] = {v.x, v.y, v.z, v.w};
    unsigned short o[4];
    const float invN = 1.0f / (float)N_NODES;
#pragma unroll
    for (int c = 0; c < 4; ++c) {
        int j = col4 + c;
        float mu  = sums[j] * invN;
        float var = sumsq[j] * invN - mu * mu;
        float sc = gamma[j] * rsqrtf(var + BN_EPS);
        float sh = beta[j] - mu * sc;
        float x = vv[c] * sc + sh;
        o[c] = f2b(fmaxf(x, 0.f));
    }
    ushort4 ov; ov.x = o[0]; ov.y = o[1]; ov.z = o[2]; ov.w = o[3];
    ((ushort4*)outbuf)[idx] = ov;
}

// ---------------- fused MLP head + softmax via MFMA: wave -> 16 nodes ----------------
__global__ __launch_bounds__(256) void k_mlp_mfma(const unsigned short* __restrict__ h,
                                                  const unsigned short* __restrict__ W1t,
                                                  const float* __restrict__ b1,
                                                  const float* __restrict__ W2,
                                                  const float* __restrict__ b2,
                                                  float* __restrict__ out) {
    int wave = threadIdx.x >> 6;
    int lane = threadIdx.x & 63;
    int col = lane & 15;
    int quad = lane >> 4;
    int row_base = blockIdx.x * 64 + wave * 16;
    if (row_base >= N_NODES) return;       // N % 16 == 0 -> all-or-nothing per wave
    int arow = row_base + col;

    f32x4 acc[4];
#pragma unroll
    for (int t = 0; t < 4; ++t) acc[t] = (f32x4){0.f, 0.f, 0.f, 0.f};

#pragma unroll
    for (int kk = 0; kk < 4; ++kk) {
        short8 a = *(const short8*)(h + (size_t)arow * D + kk * 32 + quad * 8);
#pragma unroll
        for (int t = 0; t < 4; ++t) {
            short8 b = *(const short8*)(W1t + (size_t)(t * 16 + col) * 128 + kk * 32 + quad * 8);
            acc[t] = __builtin_amdgcn_mfma_f32_16x16x32_bf16(a, b, acc[t], 0, 0, 0);
        }
    }

    // z = relu(acc + b1);  logits partials over this lane's 4 columns
    float pa[4] = {0.f, 0.f, 0.f, 0.f}, pb[4] = {0.f, 0.f, 0.f, 0.f};
#pragma unroll
    for (int t = 0; t < 4; ++t) {
        int c = t * 16 + col;
        float bb = b1[c];
        float w2a = W2[c * 2], w2b = W2[c * 2 + 1];
#pragma unroll
        for (int r = 0; r < 4; ++r) {
            float z = fmaxf(acc[t][r] + bb, 0.f);
            pa[r] = fmaf(z, w2a, pa[r]);
            pb[r] = fmaf(z, w2b, pb[r]);
        }
    }
    // butterfly reduce across the 16 lanes of the quad
#pragma unroll
    for (int m = 1; m < 16; m <<= 1) {
#pragma unroll
        for (int r = 0; r < 4; ++r) {
            pa[r] += __shfl_xor(pa[r], m);
            pb[r] += __shfl_xor(pb[r], m);
        }
    }
    if (col < 4) {
        int node = row_base + quad * 4 + col;
        float l0 = pa[col] + b2[0], l1 = pb[col] + b2[1];
        float2 lg; lg.x = l0; lg.y = l1;
        ((float2*)out)[node] = lg;
        float m = fmaxf(l0, l1);
        float e0 = expf(l0 - m), e1 = expf(l1 - m);
        float s = 1.0f / (e0 + e1);
        float2 pr; pr.x = e0 * s; pr.y = e1 * s;
        ((float2*)(out + 2 * N_NODES))[node] = pr;
    }
}

extern "C" void kernel_launch(void* const* d_in, const int* in_sizes, int n_in,
                              void* d_out, int out_size, void* d_ws, size_t ws_size,
                              hipStream_t stream) {
    const float* x     = (const float*)d_in[0];
    const int*   ei    = (const int*)d_in[1];
    const int*   src   = ei;
    const int*   dst   = ei + N_EDGES;
    const float* Wl    = (const float*)d_in[2];
    const float* Wr    = (const float*)d_in[3];
    const float* bl    = (const float*)d_in[4];
    const float* gamma = (const float*)d_in[5];
    const float* beta  = (const float*)d_in[6];
    const float* W1    = (const float*)d_in[7];
    const float* b1    = (const float*)d_in[8];
    const float* W2    = (const float*)d_in[9];
    const float* b2    = (const float*)d_in[10];
    float* out = (float*)d_out;

    char* ws = (char*)d_ws;
    size_t off = 0;
    auto alloc = [&](size_t bytes) -> void* {
        void* p = ws + off;
        off += (bytes + 255) & ~(size_t)255;
        return p;
    };
    unsigned short* xb   = (unsigned short*)alloc((size_t)N_NODES * D * 2);  // reused as 2nd h buf
    unsigned short* Ha   = (unsigned short*)alloc((size_t)N_NODES * D * 2);
    unsigned short* Mb   = (unsigned short*)alloc((size_t)N_NODES * D * 2);
    float* pre           = (float*)alloc((size_t)N_NODES * D * 4);
    unsigned short* Wtb  = (unsigned short*)alloc((size_t)NW * 2);
    unsigned short* W1t  = (unsigned short*)alloc((size_t)64 * 128 * 2);
    float* partial       = (float*)alloc((size_t)GBLK * 256 * 4);
    int* cnt             = (int*)alloc((size_t)N_NODES * 4);
    int* row_ptr         = (int*)alloc((size_t)(N_NODES + 1) * 4);
    int* row_fill        = (int*)alloc((size_t)N_NODES * 4);
    int* edge_sorted     = (int*)alloc((size_t)N_EDGES * 4);
    int* bsum            = (int*)alloc((size_t)NBLK * 4);
    int* boff            = (int*)alloc((size_t)NBLK * 4);
    float* sums          = (float*)alloc(256 * 4);
    float* sumsq = sums + 128;

    // --- converts ---
    k_cvt_x<<<(N_NODES * D / 4 + 255) / 256, 256, 0, stream>>>(x, xb);
    k_cvt_weights<<<(NW + 64 * 128 + 255) / 256, 256, 0, stream>>>(Wl, Wr, W1, Wtb, W1t);

    // --- build CSR (by dst), reused across the 3 layers ---
    hipMemsetAsync(cnt, 0, (size_t)N_NODES * 4, stream);
    k_hist<<<(N_EDGES + 255) / 256, 256, 0, stream>>>(dst, cnt);
    k_local_scan<<<NBLK, 256, 0, stream>>>(cnt, row_ptr, bsum);
    k_scan_bsums<<<1, 256, 0, stream>>>(bsum, boff, row_ptr);
    k_add_off<<<NBLK, 256, 0, stream>>>(row_ptr, boff, row_fill);
    k_fill<<<(N_EDGES + 255) / 256, 256, 0, stream>>>(src, dst, row_fill, edge_sorted);

    // --- 3 SAGE layers (h buffers ping-pong: xb -> Ha -> xb -> Ha) ---
    const unsigned short* hcur = xb;
    unsigned short* hout[3] = {Ha, xb, Ha};
    for (int l = 0; l < NLAYERS; ++l) {
        k_agg<<<N_NODES / 16, 256, 0, stream>>>(hcur, edge_sorted, row_ptr, Mb);
        k_gemm_mfma<<<GBLK, 256, 0, stream>>>(Mb, hcur, Wtb + (size_t)l * 32768,
                                              bl + l * D, pre, partial);
        k_reduce_stats<<<1, 256, 0, stream>>>(partial, sums);
        k_bnrelu<<<(N_NODES * D / 4 + 255) / 256, 256, 0, stream>>>(
            pre, sums, sumsq, gamma + l * D, beta + l * D, hout[l]);
        hcur = hout[l];
    }

    // --- fused MLP head + softmax ---
    k_mlp_mfma<<<GBLK, 256, 0, stream>>>(hcur, W1t, b1, W2, b2, out);
}

// Round 5
// 387.711 us; speedup vs baseline: 2.2977x; 1.0995x over previous
//
#include <hip/hip_runtime.h>
#include <math.h>

#define N_NODES 50000
#define N_EDGES 600000
#define D 128
#define NLAYERS 3
#define BN_EPS 1e-5f
#define NBLK ((N_NODES + 255) / 256)       // 196 scan blocks
#define GBLK ((N_NODES + 63) / 64)         // 782 layer blocks
#define NW (NLAYERS * 128 * 256)           // Wt elements
#define MPAD 136                           // LDS mean row pitch (shorts): 272B -> 2-way bank alias (free)

typedef short short8 __attribute__((ext_vector_type(8)));   // 8 bf16 (4 VGPRs)
typedef float f32x4 __attribute__((ext_vector_type(4)));

__device__ __forceinline__ float b2f(unsigned short u) {
    return __uint_as_float(((unsigned int)u) << 16);
}
__device__ __forceinline__ unsigned short f2b(float f) {  // RNE
    unsigned int b = __float_as_uint(f);
    return (unsigned short)((b + 0x7fffu + ((b >> 16) & 1u)) >> 16);
}

// ---------------- converts ----------------
__global__ void k_cvt_x(const float* __restrict__ x, unsigned short* __restrict__ xb) {
    int idx = blockIdx.x * 256 + threadIdx.x;       // float4 granule
    if (idx >= N_NODES * D / 4) return;
    float4 v = ((const float4*)x)[idx];
    ushort4 o;
    o.x = f2b(v.x); o.y = f2b(v.y); o.z = f2b(v.z); o.w = f2b(v.w);
    ((ushort4*)xb)[idx] = o;
}

// Wt[l][c][k]: k<128 -> Wl[l][k][c], k>=128 -> Wr[l][k-128][c];  W1t[c][k] = W1[k][c]
__global__ void k_cvt_weights(const float* __restrict__ Wl, const float* __restrict__ Wr,
                              const float* __restrict__ W1, unsigned short* __restrict__ Wt,
                              unsigned short* __restrict__ W1t) {
    int idx = blockIdx.x * 256 + threadIdx.x;
    if (idx < NW) {
        int l = idx >> 15;
        int rem = idx & 32767;
        int c = rem >> 8;
        int k = rem & 255;
        float v = (k < 128) ? Wl[l * 16384 + k * 128 + c]
                            : Wr[l * 16384 + (k - 128) * 128 + c];
        Wt[idx] = f2b(v);
    } else {
        int i = idx - NW;
        if (i < 64 * 128) {
            int c = i >> 7;
            int k = i & 127;
            W1t[i] = f2b(W1[k * 64 + c]);
        }
    }
}

// ---------------- CSR build ----------------
__global__ void k_hist(const int* __restrict__ dst, int* __restrict__ cnt) {
    int e = blockIdx.x * blockDim.x + threadIdx.x;
    if (e < N_EDGES) atomicAdd(&cnt[dst[e]], 1);
}

__global__ void k_local_scan(const int* __restrict__ cnt, int* __restrict__ row_ptr,
                             int* __restrict__ bsum) {
    __shared__ int sm[256];
    int tid = threadIdx.x;
    int i = blockIdx.x * 256 + tid;
    int v = (i < N_NODES) ? cnt[i] : 0;
    sm[tid] = v;
    __syncthreads();
    for (int off = 1; off < 256; off <<= 1) {
        int t = (tid >= off) ? sm[tid - off] : 0;
        __syncthreads();
        sm[tid] += t;
        __syncthreads();
    }
    int incl = sm[tid];
    if (i < N_NODES) row_ptr[i] = incl - v;
    if (tid == 255) bsum[blockIdx.x] = incl;
}

__global__ void k_scan_bsums(const int* __restrict__ bsum, int* __restrict__ boff,
                             int* __restrict__ row_ptr) {
    __shared__ int sm[256];
    int tid = threadIdx.x;
    int v = (tid < NBLK) ? bsum[tid] : 0;
    sm[tid] = v;
    __syncthreads();
    for (int off = 1; off < 256; off <<= 1) {
        int t = (tid >= off) ? sm[tid - off] : 0;
        __syncthreads();
        sm[tid] += t;
        __syncthreads();
    }
    int incl = sm[tid];
    if (tid < NBLK) boff[tid] = incl - v;
    if (tid == 255) row_ptr[N_NODES] = incl;
}

__global__ void k_add_off(int* __restrict__ row_ptr, const int* __restrict__ boff,
                          int* __restrict__ row_fill) {
    int i = blockIdx.x * 256 + threadIdx.x;
    if (i < N_NODES) {
        int v = row_ptr[i] + boff[i >> 8];
        row_ptr[i] = v;
        row_fill[i] = v;
    }
}

__global__ void k_fill(const int* __restrict__ src, const int* __restrict__ dst,
                       int* __restrict__ row_fill, int* __restrict__ edge_sorted) {
    int e = blockIdx.x * blockDim.x + threadIdx.x;
    if (e < N_EDGES) {
        int pos = atomicAdd(&row_fill[dst[e]], 1);
        edge_sorted[pos] = src[e];
    }
}

// ---------------- fused layer: gather-mean (LDS) + bf16 MFMA GEMM + atomic BN stats ----
// block = 256 thr = 4 waves, owns 64 rows x 128 cols.
// pre[n][j] = sum_k mean[n][k]*Wl[k][j] + h[n][k]*Wr[k][j] + bias[j]  (fp32 out)
__global__ __launch_bounds__(256) void k_layer(const unsigned short* __restrict__ h,
                                               const int* __restrict__ edge_sorted,
                                               const int* __restrict__ row_ptr,
                                               const unsigned short* __restrict__ Wt,
                                               const float* __restrict__ bias,
                                               float* __restrict__ pre,
                                               float* __restrict__ sums) {
    __shared__ unsigned short meanb[64][MPAD];   // bf16 mean rows, padded pitch
    __shared__ float red[4][256];

    int tid = threadIdx.x;
    int row0 = blockIdx.x * 64;

    // ---- phase A: gather-mean for this block's 64 nodes, 16 lanes/node, 4 passes ----
    {
        int sub = tid >> 4;            // 0..15
        int lane = tid & 15;           // 16B per lane covers the 256B row
        const short8* hp = (const short8*)h;
#pragma unroll
        for (int p = 0; p < 4; ++p) {
            int nl = p * 16 + sub;     // block-local node 0..63
            int node = row0 + nl;
            if (node < N_NODES) {
                int beg = row_ptr[node], end = row_ptr[node + 1];
                float a[8];
#pragma unroll
                for (int i = 0; i < 8; ++i) a[i] = 0.f;
                int e1 = end - 1;
                for (int j = beg; j < end; j += 4) {
                    int j1 = j + 1, j2 = j + 2, j3 = j + 3;
                    int i1 = (j1 <= e1) ? j1 : e1;
                    int i2 = (j2 <= e1) ? j2 : e1;
                    int i3 = (j3 <= e1) ? j3 : e1;
                    int s0 = edge_sorted[j];
                    int s1 = edge_sorted[i1];
                    int s2 = edge_sorted[i2];
                    int s3 = edge_sorted[i3];
                    short8 v0 = hp[(size_t)s0 * 16 + lane];
                    short8 v1 = hp[(size_t)s1 * 16 + lane];
                    short8 v2 = hp[(size_t)s2 * 16 + lane];
                    short8 v3 = hp[(size_t)s3 * 16 + lane];
                    float m1 = (j1 < end) ? 1.f : 0.f;
                    float m2 = (j2 < end) ? 1.f : 0.f;
                    float m3 = (j3 < end) ? 1.f : 0.f;
#pragma unroll
                    for (int i = 0; i < 8; ++i) {
                        float t = a[i] + b2f((unsigned short)v0[i]);
                        t = fmaf(m1, b2f((unsigned short)v1[i]), t);
                        t = fmaf(m2, b2f((unsigned short)v2[i]), t);
                        t = fmaf(m3, b2f((unsigned short)v3[i]), t);
                        a[i] = t;
                    }
                }
                float inv = 1.0f / fmaxf((float)(end - beg), 1.0f);
                short8 o;
#pragma unroll
                for (int i = 0; i < 8; ++i) o[i] = (short)f2b(a[i] * inv);
                *(short8*)&meanb[nl][lane * 8] = o;
            }
        }
    }
    __syncthreads();

    // ---- phase B: MFMA ----
    int wave = tid >> 6;
    int lane = tid & 63;
    int col = lane & 15;
    int quad = lane >> 4;
    int row_base = row0 + wave * 16;
    bool valid = row_base < N_NODES;     // N % 16 == 0 -> all-or-nothing per wave

    f32x4 acc[8];
#pragma unroll
    for (int t = 0; t < 8; ++t) acc[t] = (f32x4){0.f, 0.f, 0.f, 0.f};

    if (valid) {
        int arow_l = wave * 16 + col;        // block-local row for LDS mean
        int arow_g = row_base + col;         // global row for h
#pragma unroll
        for (int kk = 0; kk < 8; ++kk) {
            short8 a;
            if (kk < 4) {
                a = *(const short8*)&meanb[arow_l][kk * 32 + quad * 8];
            } else {
                a = *(const short8*)(h + (size_t)arow_g * D + (kk - 4) * 32 + quad * 8);
            }
#pragma unroll
            for (int t = 0; t < 8; ++t) {
                short8 b = *(const short8*)(Wt + (size_t)(t * 16 + col) * 256 + kk * 32 + quad * 8);
                acc[t] = __builtin_amdgcn_mfma_f32_16x16x32_bf16(a, b, acc[t], 0, 0, 0);
            }
        }
    }

    // ---- phase C: epilogue (bias, store pre, per-wave column stats) ----
#pragma unroll
    for (int t = 0; t < 8; ++t) {
        float s = 0.f, ss = 0.f;
        if (valid) {
            float bc = bias[t * 16 + col];
#pragma unroll
            for (int r = 0; r < 4; ++r) {
                float v = acc[t][r] + bc;
                pre[(size_t)(row_base + quad * 4 + r) * D + t * 16 + col] = v;
                s += v;
                ss += v * v;
            }
        }
        s += __shfl_xor(s, 16);  ss += __shfl_xor(ss, 16);
        s += __shfl_xor(s, 32);  ss += __shfl_xor(ss, 32);
        if (quad == 0) {
            red[wave][t * 16 + col] = s;
            red[wave][128 + t * 16 + col] = ss;
        }
    }
    __syncthreads();
    float pv = red[0][tid] + red[1][tid] + red[2][tid] + red[3][tid];
    atomicAdd(&sums[tid], pv);
}

// ---------------- BN apply + ReLU: fp32 pre -> bf16 h ----------------
__global__ void k_bnrelu(const float* __restrict__ pre, const float* __restrict__ sums,
                         const float* __restrict__ gamma, const float* __restrict__ beta,
                         unsigned short* __restrict__ outbuf) {
    int idx = blockIdx.x * blockDim.x + threadIdx.x;
    const int total = N_NODES * D / 4;
    if (idx >= total) return;
    const float* sumsq = sums + 128;
    int col4 = (idx & 31) * 4;
    float4 v = ((const float4*)pre)[idx];
    float vv[4] = {v.x, v.y, v.z, v.w};
    unsigned short o[4];
    const float invN = 1.0f / (float)N_NODES;
#pragma unroll
    for (int c = 0; c < 4; ++c) {
        int j = col4 + c;
        float mu  = sums[j] * invN;
        float var = sumsq[j] * invN - mu * mu;
        float sc = gamma[j] * rsqrtf(var + BN_EPS);
        float sh = beta[j] - mu * sc;
        float x = vv[c] * sc + sh;
        o[c] = f2b(fmaxf(x, 0.f));
    }
    ushort4 ov; ov.x = o[0]; ov.y = o[1]; ov.z = o[2]; ov.w = o[3];
    ((ushort4*)outbuf)[idx] = ov;
}

// ---------------- fused MLP head + softmax via MFMA: wave -> 16 nodes ----------------
__global__ __launch_bounds__(256) void k_mlp_mfma(const unsigned short* __restrict__ h,
                                                  const unsigned short* __restrict__ W1t,
                                                  const float* __restrict__ b1,
                                                  const float* __restrict__ W2,
                                                  const float* __restrict__ b2,
                                                  float* __restrict__ out) {
    int wave = threadIdx.x >> 6;
    int lane = threadIdx.x & 63;
    int col = lane & 15;
    int quad = lane >> 4;
    int row_base = blockIdx.x * 64 + wave * 16;
    if (row_base >= N_NODES) return;       // N % 16 == 0 -> all-or-nothing per wave
    int arow = row_base + col;

    f32x4 acc[4];
#pragma unroll
    for (int t = 0; t < 4; ++t) acc[t] = (f32x4){0.f, 0.f, 0.f, 0.f};

#pragma unroll
    for (int kk = 0; kk < 4; ++kk) {
        short8 a = *(const short8*)(h + (size_t)arow * D + kk * 32 + quad * 8);
#pragma unroll
        for (int t = 0; t < 4; ++t) {
            short8 b = *(const short8*)(W1t + (size_t)(t * 16 + col) * 128 + kk * 32 + quad * 8);
            acc[t] = __builtin_amdgcn_mfma_f32_16x16x32_bf16(a, b, acc[t], 0, 0, 0);
        }
    }

    float pa[4] = {0.f, 0.f, 0.f, 0.f}, pb[4] = {0.f, 0.f, 0.f, 0.f};
#pragma unroll
    for (int t = 0; t < 4; ++t) {
        int c = t * 16 + col;
        float bb = b1[c];
        float w2a = W2[c * 2], w2b = W2[c * 2 + 1];
#pragma unroll
        for (int r = 0; r < 4; ++r) {
            float z = fmaxf(acc[t][r] + bb, 0.f);
            pa[r] = fmaf(z, w2a, pa[r]);
            pb[r] = fmaf(z, w2b, pb[r]);
        }
    }
#pragma unroll
    for (int m = 1; m < 16; m <<= 1) {
#pragma unroll
        for (int r = 0; r < 4; ++r) {
            pa[r] += __shfl_xor(pa[r], m);
            pb[r] += __shfl_xor(pb[r], m);
        }
    }
    if (col < 4) {
        int node = row_base + quad * 4 + col;
        float l0 = pa[col] + b2[0], l1 = pb[col] + b2[1];
        float2 lg; lg.x = l0; lg.y = l1;
        ((float2*)out)[node] = lg;
        float m = fmaxf(l0, l1);
        float e0 = expf(l0 - m), e1 = expf(l1 - m);
        float s = 1.0f / (e0 + e1);
        float2 pr; pr.x = e0 * s; pr.y = e1 * s;
        ((float2*)(out + 2 * N_NODES))[node] = pr;
    }
}

extern "C" void kernel_launch(void* const* d_in, const int* in_sizes, int n_in,
                              void* d_out, int out_size, void* d_ws, size_t ws_size,
                              hipStream_t stream) {
    const float* x     = (const float*)d_in[0];
    const int*   ei    = (const int*)d_in[1];
    const int*   src   = ei;
    const int*   dst   = ei + N_EDGES;
    const float* Wl    = (const float*)d_in[2];
    const float* Wr    = (const float*)d_in[3];
    const float* bl    = (const float*)d_in[4];
    const float* gamma = (const float*)d_in[5];
    const float* beta  = (const float*)d_in[6];
    const float* W1    = (const float*)d_in[7];
    const float* b1    = (const float*)d_in[8];
    const float* W2    = (const float*)d_in[9];
    const float* b2    = (const float*)d_in[10];
    float* out = (float*)d_out;

    char* ws = (char*)d_ws;
    size_t off = 0;
    auto alloc = [&](size_t bytes) -> void* {
        void* p = ws + off;
        off += (bytes + 255) & ~(size_t)255;
        return p;
    };
    unsigned short* xb   = (unsigned short*)alloc((size_t)N_NODES * D * 2);  // reused as 2nd h buf
    unsigned short* Ha   = (unsigned short*)alloc((size_t)N_NODES * D * 2);
    float* pre           = (float*)alloc((size_t)N_NODES * D * 4);
    unsigned short* Wtb  = (unsigned short*)alloc((size_t)NW * 2);
    unsigned short* W1t  = (unsigned short*)alloc((size_t)64 * 128 * 2);
    int* cnt             = (int*)alloc((size_t)N_NODES * 4);
    int* row_ptr         = (int*)alloc((size_t)(N_NODES + 1) * 4);
    int* row_fill        = (int*)alloc((size_t)N_NODES * 4);
    int* edge_sorted     = (int*)alloc((size_t)N_EDGES * 4);
    int* bsum            = (int*)alloc((size_t)NBLK * 4);
    int* boff            = (int*)alloc((size_t)NBLK * 4);
    float* sums_all      = (float*)alloc(NLAYERS * 256 * 4);  // per-layer [sums|sumsq]

    // --- converts ---
    k_cvt_x<<<(N_NODES * D / 4 + 255) / 256, 256, 0, stream>>>(x, xb);
    k_cvt_weights<<<(NW + 64 * 128 + 255) / 256, 256, 0, stream>>>(Wl, Wr, W1, Wtb, W1t);

    // --- build CSR (by dst), reused across the 3 layers ---
    hipMemsetAsync(cnt, 0, (size_t)N_NODES * 4, stream);
    k_hist<<<(N_EDGES + 255) / 256, 256, 0, stream>>>(dst, cnt);
    k_local_scan<<<NBLK, 256, 0, stream>>>(cnt, row_ptr, bsum);
    k_scan_bsums<<<1, 256, 0, stream>>>(bsum, boff, row_ptr);
    k_add_off<<<NBLK, 256, 0, stream>>>(row_ptr, boff, row_fill);
    k_fill<<<(N_EDGES + 255) / 256, 256, 0, stream>>>(src, dst, row_fill, edge_sorted);

    // zero all per-layer BN stat slots once
    hipMemsetAsync(sums_all, 0, NLAYERS * 256 * 4, stream);

    // --- 3 SAGE layers (h buffers ping-pong: xb -> Ha -> xb -> Ha) ---
    const unsigned short* hcur = xb;
    unsigned short* hout[3] = {Ha, xb, Ha};
    for (int l = 0; l < NLAYERS; ++l) {
        float* sums = sums_all + l * 256;
        k_layer<<<GBLK, 256, 0, stream>>>(hcur, edge_sorted, row_ptr,
                                          Wtb + (size_t)l * 32768, bl + l * D, pre, sums);
        k_bnrelu<<<(N_NODES * D / 4 + 255) / 256, 256, 0, stream>>>(
            pre, sums, gamma + l * D, beta + l * D, hout[l]);
        hcur = hout[l];
    }

    // --- fused MLP head + softmax ---
    k_mlp_mfma<<<GBLK, 256, 0, stream>>>(hcur, W1t, b1, W2, b2, out);
}